// Round 1
// baseline (183.603 us; speedup 1.0000x reference)
//
#include <hip/hip_runtime.h>
#include <math.h>

// Problem constants (fixed by setup_inputs)
#define W_ 192
#define H_ 192
#define D_ 160
#define B_ 2
#define CHUNK 40          // z-planes of output per block
#define TILE 16
#define HALO 20           // TILE + 4 (window 5, pad 2)
#define NTOT 11796480.0f  // 2*1*160*192*192

struct Q { float ss, tt, s2, t2, st; };

__global__ __launch_bounds__(256) void lncc_main(const float* __restrict__ src,
                                                 const float* __restrict__ tgt,
                                                 float* __restrict__ acc) {
    __shared__ float2 tileP[HALO][HALO];   // interleaved (s, t)
    __shared__ float  wsum[4];

    const int tx  = threadIdx.x, ty = threadIdx.y;
    const int tid = ty * TILE + tx;
    const int bz  = blockIdx.z;
    const int b   = bz >> 2;               // D_/CHUNK == 4 chunks per batch
    const int z0  = (bz & 3) * CHUNK;
    const int bx0 = blockIdx.x * TILE - 2;
    const int by0 = blockIdx.y * TILE - 2;

    Q r0 = {}, r1 = {}, r2 = {}, r3 = {}, r4 = {};
    float lsum = 0.0f;

    for (int zp = z0 - 2; zp < z0 + CHUNK + 2; ++zp) {
        Q cur = {};
        if (zp >= 0 && zp < D_) {
            __syncthreads();   // previous plane's readers done before overwrite
            const size_t planeBase = (size_t)(b * D_ + zp) * (size_t)(H_ * W_);
            for (int f = tid; f < HALO * HALO; f += TILE * TILE) {
                int r  = f / HALO;
                int c  = f - r * HALO;
                int gy = by0 + r, gx = bx0 + c;
                float sv = 0.0f, tv = 0.0f;
                if (gx >= 0 && gx < W_ && gy >= 0 && gy < H_) {
                    size_t idx = planeBase + (size_t)gy * W_ + (size_t)gx;
                    sv = src[idx];
                    tv = tgt[idx];
                }
                tileP[r][c] = make_float2(sv, tv);
            }
            __syncthreads();
            #pragma unroll
            for (int dy = 0; dy < 5; ++dy) {
                #pragma unroll
                for (int dx = 0; dx < 5; ++dx) {
                    float2 v = tileP[ty + dy][tx + dx];
                    cur.ss += v.x;
                    cur.tt += v.y;
                    cur.s2 = fmaf(v.x, v.x, cur.s2);
                    cur.t2 = fmaf(v.y, v.y, cur.t2);
                    cur.st = fmaf(v.x, v.y, cur.st);
                }
            }
        }
        // shift ring (register renames, no runtime indexing -> no scratch)
        r0 = r1; r1 = r2; r2 = r3; r3 = r4; r4 = cur;

        if (zp >= z0 + 2) {   // output voxel z = zp - 2 is complete
            const float inv = 1.0f / 125.0f;
            float ssum  = r0.ss + r1.ss + r2.ss + r3.ss + r4.ss;
            float tsum  = r0.tt + r1.tt + r2.tt + r3.tt + r4.tt;
            float s2sum = r0.s2 + r1.s2 + r2.s2 + r3.s2 + r4.s2;
            float t2sum = r0.t2 + r1.t2 + r2.t2 + r3.t2 + r4.t2;
            float stsum = r0.st + r1.st + r2.st + r3.st + r4.st;
            float ms = ssum * inv, mt = tsum * inv;
            float vs = s2sum * inv - ms * ms;
            float vt = t2sum * inv - mt * mt;
            float cr = stsum * inv - ms * mt;
            lsum += cr * cr / (vs * vt + 1e-5f);
        }
    }

    // block reduction: wave shuffle, then across the 4 waves via LDS
    #pragma unroll
    for (int off = 32; off > 0; off >>= 1)
        lsum += __shfl_down(lsum, off, 64);
    if ((tid & 63) == 0) wsum[tid >> 6] = lsum;
    __syncthreads();
    if (tid == 0) {
        float t = wsum[0] + wsum[1] + wsum[2] + wsum[3];
        atomicAdd(acc, t);
    }
}

__global__ void lncc_zero(float* acc) { *acc = 0.0f; }

__global__ void lncc_finalize(const float* __restrict__ acc, float* __restrict__ out) {
    float loss = 1.0f - (*acc) * (1.0f / NTOT);
    if (isnan(loss) || isinf(loss)) loss = 1.0f;
    *out = loss;
}

extern "C" void kernel_launch(void* const* d_in, const int* in_sizes, int n_in,
                              void* d_out, int out_size, void* d_ws, size_t ws_size,
                              hipStream_t stream) {
    const float* src = (const float*)d_in[0];
    const float* tgt = (const float*)d_in[1];
    float* out = (float*)d_out;
    float* acc = (float*)d_ws;   // one fp32 accumulator in workspace

    lncc_zero<<<dim3(1), dim3(1), 0, stream>>>(acc);

    dim3 grid(W_ / TILE, H_ / TILE, B_ * (D_ / CHUNK));  // 12 x 12 x 8
    dim3 block(TILE, TILE, 1);
    lncc_main<<<grid, block, 0, stream>>>(src, tgt, acc);

    lncc_finalize<<<dim3(1), dim3(1), 0, stream>>>(acc, out);
}